// Round 10
// baseline (27188.950 us; speedup 1.0000x reference)
//
#include <hip/hip_runtime.h>
#include <hip/hip_bf16.h>

// BiLSTM(512/dir, T=8192) + linear(9) + Viterbi decode.
//  K1 gemm_xproj : 128x128 tile, 8x8 register blocking (VALU fp32; no fp32 MFMA on CDNA4)
//  K2 lstm_scan  : 32 FAT persistent blocks (16/dir) x 1024 threads (16 waves, 1 CU each,
//                  128 VGPR/lane). Block owns 32 h values; 64 weights/lane in VGPRs.
//                  Per step: waves 0..3 poll h(t-1) (1 u64/lane, dedup across waves;
//                  coupling degree 4 producers/wave), stage to bank-padded LDS (dbuf),
//                  LDS release-counter; ALL waves spin on the LDS counter (acquire) --
//                  no s_barrier, no global spin for 12/16 waves. Dot: 1 row x 64 k per
//                  lane (8-way broadcast LDS reads), butterfly over 8 k-lanes, gates on
//                  2 lanes/wave, u64 agent-atomic h store (1/wave).
//                  2-buffer staging is safe: re-staging buffer p requires the device to
//                  have consumed our own slowest wave's step-s store (self-throttling).
//  K3 feats      : feats[t,n] = [h_f|h_b] @ W_out^T + b_out
//  K4 viterbi    : single wave; backpointers packed 4b x 9 into u64/step.
//
// ws layout (floats):
//   [0)                 xprojb   8192*4096            = 128 MB
//   [+8192*4096)        h_seq    2*8192*512           =  32 MB (poisoned 0x7F each launch)
//   [+2*8192*512)       feats    8192*9
//   [then]              bpw      8192 u64

#define T_SEQ   8192
#define EMB     512
#define HDIM    512
#define POISON64 0x7F7F7F7F7F7F7F7Full  // |h|<1 so never produced

#define ALOAD(p)     __hip_atomic_load((p), __ATOMIC_RELAXED, __HIP_MEMORY_SCOPE_AGENT)
#define ASTORE(p, v) __hip_atomic_store((p), (v), __ATOMIC_RELAXED, __HIP_MEMORY_SCOPE_AGENT)

// ---------------------------------------------------------------- K1: GEMM
__global__ __launch_bounds__(256) void gemm_xproj(
    const int* __restrict__ sentence, const float* __restrict__ emb,
    const float* __restrict__ Wih_f, const float* __restrict__ Wih_b,
    const float* __restrict__ bih_f, const float* __restrict__ bhh_f,
    const float* __restrict__ bih_b, const float* __restrict__ bhh_b,
    float* __restrict__ xprojb)
{
    __shared__ float As[16][132];      // [kk][row], pad to 132 floats
    __shared__ float Bs[16][132];
    __shared__ int   srow[128];

    const int tid = threadIdx.x;
    const int bm = blockIdx.x;          // 64 tiles of 128 t
    const int bn = blockIdx.y;          // 32 tiles of 128 j (0..15 fwd, 16..31 bwd)
    const int fwd = (bn < 16);
    const float* __restrict__ W = fwd ? Wih_f : Wih_b;
    const int jbase = bn * 128 - (fwd ? 0 : 2048);

    if (tid < 128) srow[tid] = sentence[bm * 128 + tid];
    __syncthreads();

    const int lkk = tid & 15;           // staging k index
    const int lr  = tid >> 4;           // staging row group (8 rows)
    int sr[8];
    #pragma unroll
    for (int i = 0; i < 8; ++i) sr[i] = srow[lr * 8 + i];
    const float* wbase = W + (size_t)(jbase + lr * 8) * EMB + lkk;

    const int tx = tid & 15, ty = tid >> 4;
    float acc[8][8] = {};

    for (int kb = 0; kb < 32; ++kb) {
        const int k0 = kb * 16;
        #pragma unroll
        for (int i = 0; i < 8; ++i) {
            As[lkk][lr * 8 + i] = emb[(size_t)sr[i] * EMB + k0 + lkk];
            Bs[lkk][lr * 8 + i] = wbase[(size_t)i * EMB + k0];
        }
        __syncthreads();
        #pragma unroll
        for (int kk = 0; kk < 16; ++kk) {
            const float4 a0 = *(const float4*)&As[kk][ty * 8];
            const float4 a1 = *(const float4*)&As[kk][ty * 8 + 4];
            const float4 b0 = *(const float4*)&Bs[kk][tx * 8];
            const float4 b1 = *(const float4*)&Bs[kk][tx * 8 + 4];
            const float av[8] = {a0.x,a0.y,a0.z,a0.w,a1.x,a1.y,a1.z,a1.w};
            const float bv[8] = {b0.x,b0.y,b0.z,b0.w,b1.x,b1.y,b1.z,b1.w};
            #pragma unroll
            for (int i = 0; i < 8; ++i)
                #pragma unroll
                for (int j = 0; j < 8; ++j)
                    acc[i][j] = fmaf(av[i], bv[j], acc[i][j]);
        }
        __syncthreads();
    }

    const float* b1p = fwd ? bih_f : bih_b;
    const float* b2p = fwd ? bhh_f : bhh_b;
    float bias[8];
    #pragma unroll
    for (int j = 0; j < 8; ++j) {
        const int jj = jbase + tx * 8 + j;
        bias[j] = b1p[jj] + b2p[jj];
    }
    #pragma unroll
    for (int i = 0; i < 8; ++i) {
        const int t = bm * 128 + ty * 8 + i;
        float4* dst = (float4*)&xprojb[(size_t)t * 4096 + bn * 128 + tx * 8];
        dst[0] = make_float4(acc[i][0] + bias[0], acc[i][1] + bias[1],
                             acc[i][2] + bias[2], acc[i][3] + bias[3]);
        dst[1] = make_float4(acc[i][4] + bias[4], acc[i][5] + bias[5],
                             acc[i][6] + bias[6], acc[i][7] + bias[7]);
    }
}

// ------------------------------------------------------------- K2: LSTM scan
__device__ __forceinline__ float fsig(float x) { return 1.0f / (1.0f + __expf(-x)); }
__device__ __forceinline__ float ftanh(float x) {
    const float e = __expf(-2.0f * fabsf(x));
    return copysignf((1.0f - e) / (1.0f + e), x);
}
__device__ __forceinline__ unsigned long long pack2(float a, float b) {
    return (unsigned long long)__float_as_uint(a) |
           ((unsigned long long)__float_as_uint(b) << 32);
}
__device__ __forceinline__ float2 unpack2(unsigned long long u) {
    return make_float2(__uint_as_float((unsigned)(u & 0xffffffffull)),
                       __uint_as_float((unsigned)(u >> 32)));
}

__global__ __launch_bounds__(1024, 4) void lstm_scan(
    const float* __restrict__ xprojb,
    const float* __restrict__ Whh_f, const float* __restrict__ Whh_b,
    float* __restrict__ hseq)
{
    const int tid  = threadIdx.x;
    const int lane = tid & 63;
    const int w    = tid >> 6;          // wave 0..15; wave owns h indices {2w, 2w+1}
    const int blk  = blockIdx.x;        // 0..31
    const int dir  = blk & 1;
    const int sub  = blk >> 1;          // 0..15; block owns h[sub*32 .. sub*32+32)
    const float* __restrict__ Whh = dir ? Whh_b : Whh_f;
    float* hs = hseq + (size_t)dir * T_SEQ * HDIM;

    const int j  = lane >> 3;           // 0..7: row-of-wave
    const int kk = lane & 7;            // k-segment of 64 (k in [64kk, 64kk+64))
    const int g  = j >> 1;              // gate 0..3 (i,f,g,o)
    const int b  = j & 1;               // which of the wave's two h values
    const int m  = 2 * w + b;           // block-local h index 0..31

    // 64 weights/lane: row g*512 + sub*32 + m, k in [64kk, 64kk+64)
    float wr[64];
    {
        const float* src = Whh + (size_t)(g * 512 + sub * 32 + m) * 512 + kk * 64;
        #pragma unroll
        for (int i = 0; i < 16; ++i) {
            const float4 v = *(const float4*)(src + 4 * i);
            wr[4*i] = v.x; wr[4*i+1] = v.y; wr[4*i+2] = v.z; wr[4*i+3] = v.w;
        }
    }

    // staged h, double-buffered, bank-padded: seg kk at [kk][0..63] of 68-float rows
    __shared__ __align__(16) float hsh[2][8][68];
    __shared__ unsigned int cnt;        // monotonic: +4 per step (one per polling wave)
    if (tid == 0) cnt = 0u;
    __syncthreads();                    // the ONLY barrier

    const bool poller = (w < 4);        // waves 0..3 poll chunk w (64 u64 each)
    const bool gl = (kk == 0) && (g == 0);   // lanes 0 and 8: gate finalizers
    float c_state = 0.0f;

    #pragma unroll 1
    for (int s = 0; s < T_SEQ; ++s) {
        const int t = dir ? (T_SEQ - 1 - s) : s;
        const int p = s & 1;

        // xproj for this wave's two h values (gl lanes) — hides under poll/spin
        float xp0 = 0.f, xp1 = 0.f, xp2 = 0.f, xp3 = 0.f;
        if (gl) {
            const float* xr = xprojb + (size_t)t * 4096 + dir * 2048 + sub * 32 + m;
            xp0 = xr[0]; xp1 = xr[512]; xp2 = xr[1024]; xp3 = xr[1536];
        }

        if (poller) {
            // poll u64 index w*64 + lane of h(t-1): covers producers sub' = 4w..4w+3
            float2 hv2;
            if (s == 0) {
                hv2 = make_float2(0.f, 0.f);
            } else {
                const int tprev = dir ? (t + 1) : (t - 1);
                const unsigned long long* hp =
                    (const unsigned long long*)(hs + (size_t)tprev * HDIM) + w * 64 + lane;
                unsigned long long u = ALOAD(hp);
                while (u == POISON64) u = ALOAD(hp);
                hv2 = unpack2(u);
            }
            // k = w*128 + 2*lane -> seg w*2+(lane>>5), offset 2*(lane&31)
            *(float2*)&hsh[p][w * 2 + (lane >> 5)][2 * (lane & 31)] = hv2;
            if (lane == 0)   // release orders this wave's ds_writes before the add
                __hip_atomic_fetch_add(&cnt, 1u, __ATOMIC_RELEASE,
                                       __HIP_MEMORY_SCOPE_WORKGROUP);
        }

        // all 16 waves wait until the 4 polling waves staged this step
        const unsigned target = 4u * (unsigned)(s + 1);
        while (__hip_atomic_load(&cnt, __ATOMIC_ACQUIRE,
                                 __HIP_MEMORY_SCOPE_WORKGROUP) < target) {}

        // dot: 1 row x 64 k per lane; 8-way broadcast reads, pad 68 spreads kk banks
        float a0 = 0.f, a1 = 0.f, a2 = 0.f, a3 = 0.f;
        const float4* h4 = (const float4*)&hsh[p][kk][0];
        #pragma unroll
        for (int i = 0; i < 16; ++i) {
            const float4 hv = h4[i];
            a0 = fmaf(wr[4*i],   hv.x, a0);
            a1 = fmaf(wr[4*i+1], hv.y, a1);
            a2 = fmaf(wr[4*i+2], hv.z, a2);
            a3 = fmaf(wr[4*i+3], hv.w, a3);
        }
        float acc = (a0 + a1) + (a2 + a3);
        // butterfly over the 8 k-lanes of this row
        acc += __shfl_xor(acc, 1);
        acc += __shfl_xor(acc, 2);
        acc += __shfl_xor(acc, 4);

        // gather gate sums: row (g,b) sits at lane g*16 + b*8
        float h = 0.f;
        if (gl) {   // lanes 0 (b=0) and 8 (b=1)
            const float si = acc;                        // own: g=0
            const float sf = __shfl(acc, 16 + lane);
            const float sg = __shfl(acc, 32 + lane);
            const float so = __shfl(acc, 48 + lane);
            const float i_ = fsig(si + xp0);
            const float f_ = fsig(sf + xp1);
            const float g_ = ftanh(sg + xp2);
            const float o_ = fsig(so + xp3);
            c_state = fmaf(f_, c_state, i_ * g_);
            h = o_ * ftanh(c_state);
        }
        // publish the wave's two h values as one u64 (no tearing)
        const float h1 = __shfl(h, 8);
        if (lane == 0) {
            unsigned long long* hdst =
                (unsigned long long*)(hs + (size_t)t * HDIM) + sub * 16 + w;
            ASTORE(hdst, pack2(h, h1));
        }
    }
}

// ---------------------------------------------------------------- K3: feats
__global__ __launch_bounds__(256) void feats_kernel(
    const float* __restrict__ hseq, const float* __restrict__ W_out,
    const float* __restrict__ b_out, float* __restrict__ feats)
{
    const int idx = blockIdx.x * 256 + threadIdx.x;   // (t, n)
    if (idx >= T_SEQ * 9) return;
    const int t = idx / 9;
    const int n = idx - t * 9;
    const float4* hf = (const float4*)(hseq + (size_t)t * HDIM);
    const float4* hb = (const float4*)(hseq + (size_t)(T_SEQ + t) * HDIM);
    const float4* wf = (const float4*)(W_out + (size_t)n * 1024);
    const float4* wb = wf + 128;
    float acc = b_out[n];
    #pragma unroll 8
    for (int i = 0; i < 128; ++i) {
        const float4 a = hf[i], w = wf[i];
        acc = fmaf(a.x, w.x, acc); acc = fmaf(a.y, w.y, acc);
        acc = fmaf(a.z, w.z, acc); acc = fmaf(a.w, w.w, acc);
    }
    #pragma unroll 8
    for (int i = 0; i < 128; ++i) {
        const float4 a = hb[i], w = wb[i];
        acc = fmaf(a.x, w.x, acc); acc = fmaf(a.y, w.y, acc);
        acc = fmaf(a.z, w.z, acc); acc = fmaf(a.w, w.w, acc);
    }
    feats[idx] = acc;
}

// --------------------------------------------------------------- K4: viterbi
__global__ __launch_bounds__(64) void viterbi_kernel(
    const float* __restrict__ feats, const float* __restrict__ trans,
    unsigned long long* __restrict__ bpw, float* __restrict__ out)
{
    const int lane = threadIdx.x;
    __shared__ __align__(16) float flds[1024 * 9];
    __shared__ unsigned char path_lds[T_SEQ];

    float tr[9];
    #pragma unroll
    for (int p = 0; p < 9; ++p) tr[p] = 0.f;
    float tstop = 0.f;
    if (lane < 9) {
        #pragma unroll
        for (int p = 0; p < 9; ++p) tr[p] = trans[lane * 9 + p];
        tstop = trans[8 * 9 + lane];
    }
    float fv = (lane == 7) ? 0.0f : -10000.0f;        // START_IDX = 7

    for (int ch = 0; ch < 8; ++ch) {
        const float4* src = (const float4*)(feats + (size_t)ch * 9216);
        #pragma unroll
        for (int i = 0; i < 36; ++i)
            ((float4*)flds)[lane + i * 64] = src[lane + i * 64];
        __syncthreads();

        for (int tt = 0; tt < 1024; ++tt) {
            const int t = ch * 1024 + tt;
            const float f0 = __shfl(fv, 0), f1 = __shfl(fv, 1), f2 = __shfl(fv, 2);
            const float f3 = __shfl(fv, 3), f4 = __shfl(fv, 4), f5 = __shfl(fv, 5);
            const float f6 = __shfl(fv, 6), f7 = __shfl(fv, 7), f8 = __shfl(fv, 8);
            const float s0 = f0 + tr[0], s1 = f1 + tr[1], s2 = f2 + tr[2];
            const float s3 = f3 + tr[3], s4 = f4 + tr[4], s5 = f5 + tr[5];
            const float s6 = f6 + tr[6], s7 = f7 + tr[7], s8 = f8 + tr[8];
            const float mx = fmaxf(fmaxf(fmaxf(fmaxf(s0, s1), fmaxf(s2, s3)),
                                         fmaxf(fmaxf(s4, s5), fmaxf(s6, s7))), s8);
            const unsigned bits =
                (s0 >= mx ? 1u : 0u)   | (s1 >= mx ? 2u : 0u)   | (s2 >= mx ? 4u : 0u) |
                (s3 >= mx ? 8u : 0u)   | (s4 >= mx ? 16u : 0u)  | (s5 >= mx ? 32u : 0u) |
                (s6 >= mx ? 64u : 0u)  | (s7 >= mx ? 128u : 0u) | (s8 >= mx ? 256u : 0u);
            const int bi = __ffs(bits) - 1;
            const float feat = (lane < 9) ? flds[tt * 9 + lane] : 0.0f;
            fv = mx + feat;
            const unsigned long long b0 = __ballot(bi & 1);
            const unsigned long long b1 = __ballot(bi & 2);
            const unsigned long long b2 = __ballot(bi & 4);
            const unsigned long long b3 = __ballot(bi & 8);
            if (lane == 0) {
                bpw[t] = (b0 & 511ull) | ((b1 & 511ull) << 9) |
                         ((b2 & 511ull) << 18) | ((b3 & 511ull) << 27);
            }
        }
        __syncthreads();
    }

    const float term = fv + tstop;
    const float t0 = __shfl(term, 0), t1 = __shfl(term, 1), t2 = __shfl(term, 2);
    const float t3 = __shfl(term, 3), t4 = __shfl(term, 4), t5 = __shfl(term, 5);
    const float t6 = __shfl(term, 6), t7 = __shfl(term, 7), t8 = __shfl(term, 8);
    const float mxt = fmaxf(fmaxf(fmaxf(fmaxf(t0, t1), fmaxf(t2, t3)),
                                  fmaxf(fmaxf(t4, t5), fmaxf(t6, t7))), t8);
    const unsigned bitst =
        (t0 >= mxt ? 1u : 0u)   | (t1 >= mxt ? 2u : 0u)   | (t2 >= mxt ? 4u : 0u) |
        (t3 >= mxt ? 8u : 0u)   | (t4 >= mxt ? 16u : 0u)  | (t5 >= mxt ? 32u : 0u) |
        (t6 >= mxt ? 64u : 0u)  | (t7 >= mxt ? 128u : 0u) | (t8 >= mxt ? 256u : 0u);
    const int best = __ffs(bitst) - 1;

    if (lane == 0) {
        out[0] = mxt;
        int c = best;
        path_lds[T_SEQ - 1] = (unsigned char)c;
        for (int thi = T_SEQ - 2; thi >= 15; thi -= 16) {
            const int tlo = thi - 15;
            unsigned long long wbuf[16];
            #pragma unroll
            for (int i = 0; i < 16; ++i) wbuf[i] = bpw[tlo + 1 + i];
            #pragma unroll
            for (int i = 15; i >= 0; --i) {
                const unsigned long long wvv = wbuf[i];
                c = (int)((wvv >> c) & 1ull) |
                    ((int)((wvv >> (9 + c)) & 1ull) << 1) |
                    ((int)((wvv >> (18 + c)) & 1ull) << 2) |
                    ((int)((wvv >> (27 + c)) & 1ull) << 3);
                path_lds[tlo + i] = (unsigned char)c;
            }
        }
        for (int t2i = 14; t2i >= 0; --t2i) {
            const unsigned long long wvv = bpw[t2i + 1];
            c = (int)((wvv >> c) & 1ull) |
                ((int)((wvv >> (9 + c)) & 1ull) << 1) |
                ((int)((wvv >> (18 + c)) & 1ull) << 2) |
                ((int)((wvv >> (27 + c)) & 1ull) << 3);
            path_lds[t2i] = (unsigned char)c;
        }
    }
    __syncthreads();
    #pragma unroll 4
    for (int i = 0; i < T_SEQ / 64; ++i) {
        const int t = i * 64 + lane;
        out[1 + t] = (float)path_lds[t];
    }
}

// ------------------------------------------------------------------- launch
extern "C" void kernel_launch(void* const* d_in, const int* in_sizes, int n_in,
                              void* d_out, int out_size, void* d_ws, size_t ws_size,
                              hipStream_t stream)
{
    (void)in_sizes; (void)n_in; (void)out_size; (void)ws_size;

    const int*   sentence = (const int*)  d_in[0];
    const float* emb      = (const float*)d_in[1];
    const float* Wih_f    = (const float*)d_in[2];
    const float* Whh_f    = (const float*)d_in[3];
    const float* bih_f    = (const float*)d_in[4];
    const float* bhh_f    = (const float*)d_in[5];
    const float* Wih_b    = (const float*)d_in[6];
    const float* Whh_b    = (const float*)d_in[7];
    const float* bih_b    = (const float*)d_in[8];
    const float* bhh_b    = (const float*)d_in[9];
    const float* W_out    = (const float*)d_in[10];
    const float* b_out    = (const float*)d_in[11];
    const float* trans    = (const float*)d_in[12];

    float* ws      = (float*)d_ws;
    float* xprojb  = ws;                                        // 8192*4096
    float* hseq    = ws + (size_t)T_SEQ * 4096;                 // 2*8192*512
    float* feats   = hseq + (size_t)2 * T_SEQ * HDIM;           // 8192*9
    unsigned long long* bpw = (unsigned long long*)(feats + (size_t)T_SEQ * 9);

    // re-poison the h exchange buffer every launch (graph replay safety)
    hipMemsetAsync(hseq, 0x7F, (size_t)2 * T_SEQ * HDIM * sizeof(float), stream);

    gemm_xproj<<<dim3(64, 32), 256, 0, stream>>>(
        sentence, emb, Wih_f, Wih_b, bih_f, bhh_f, bih_b, bhh_b, xprojb);

    lstm_scan<<<dim3(32), 1024, 0, stream>>>(
        xprojb, Whh_f, Whh_b, hseq);

    feats_kernel<<<dim3((T_SEQ * 9 + 255) / 256), 256, 0, stream>>>(
        hseq, W_out, b_out, feats);

    viterbi_kernel<<<dim3(1), 64, 0, stream>>>(feats, trans, bpw, (float*)d_out);
}

// Round 11
// 20003.319 us; speedup vs baseline: 1.3592x; 1.3592x over previous
//
#include <hip/hip_runtime.h>
#include <hip/hip_bf16.h>

// BiLSTM(512/dir, T=8192) + linear(9) + Viterbi decode.
//  K_fused: grid = 32 LSTM blocks + 2048 GEMM blocks, 640 threads each.
//   - LSTM blocks (blockIdx < 32): TWO independent R2-protocol units per block
//     (unit0 = fwd, unit1 = bwd), 5 waves each: wave0 coordinator (gates/c-state/
//     h-store) + 4 k-chunk waves (128 Whh floats/lane). Co-located on one CU so
//     each unit's poll stalls hide under the other unit's compute (m114).
//     Poison-poll h (agent relaxed u64), LDS staging, monotonic cnt (rel/acq),
//     own-slice LDS forward. Coordinator also poison-checks its 4 xproj values
//     (xprojb produced concurrently by the GEMM blocks).
//   - GEMM blocks (blockIdx >= 32): xproj = emb[sentence] @ Wih^T + bias,
//     128x128 tile, 8x8 register blocking, 256 active threads (waves 4..9 only
//     participate in barriers). bm tiles produced from BOTH sequence ends so
//     fwd (t=0..) and bwd (t=8191..) consumers start immediately.
//  K3 feats   : feats[t,n] = [h_f|h_b] @ W_out^T + b_out
//  K4 viterbi : single wave; backpointers packed 4b x 9 into u64/step.
//
// ws layout (floats):
//   [0)                 xprojb   8192*4096  = 128 MB (poisoned 0x7F each launch)
//   [+8192*4096)        h_seq    2*8192*512 =  32 MB (poisoned 0x7F each launch)
//   [+2*8192*512)       feats    8192*9
//   [then]              bpw      8192 u64

#define T_SEQ   8192
#define EMB     512
#define HDIM    512
#define SLICE   16
#define POISON64 0x7F7F7F7F7F7F7F7Full
#define POISON32 0x7F7F7F7Fu

#define ALOAD(p)      __hip_atomic_load((p), __ATOMIC_RELAXED, __HIP_MEMORY_SCOPE_AGENT)
#define ASTORE(p, v)  __hip_atomic_store((p), (v), __ATOMIC_RELAXED, __HIP_MEMORY_SCOPE_AGENT)
#define ALOAD32(p)    __hip_atomic_load((p), __ATOMIC_RELAXED, __HIP_MEMORY_SCOPE_AGENT)

__device__ __forceinline__ float fsig(float x) { return 1.0f / (1.0f + __expf(-x)); }
__device__ __forceinline__ float ftanh(float x) {
    const float e = __expf(-2.0f * fabsf(x));
    return copysignf((1.0f - e) / (1.0f + e), x);
}
__device__ __forceinline__ unsigned long long pack2(float a, float b) {
    return (unsigned long long)__float_as_uint(a) |
           ((unsigned long long)__float_as_uint(b) << 32);
}
__device__ __forceinline__ float2 unpack2(unsigned long long u) {
    return make_float2(__uint_as_float((unsigned)(u & 0xffffffffull)),
                       __uint_as_float((unsigned)(u >> 32)));
}

// ---------------------------------------------------------- fused GEMM+LSTM
__global__ __launch_bounds__(640, 1) void fused_main(
    const int* __restrict__ sentence, const float* __restrict__ emb,
    const float* __restrict__ Wih_f, const float* __restrict__ Wih_b,
    const float* __restrict__ bih_f, const float* __restrict__ bhh_f,
    const float* __restrict__ bih_b, const float* __restrict__ bhh_b,
    const float* __restrict__ Whh_f, const float* __restrict__ Whh_b,
    float* __restrict__ xprojb, float* __restrict__ hseq)
{
    __shared__ float As[16][132];
    __shared__ float Bs[16][132];
    __shared__ int   srow[128];
    __shared__ __align__(16) float hst[2][2][4][128];      // [unit][par][chunk][]
    __shared__ __align__(16) float partials[2][2][4][64];  // [unit][par][chunk][]
    __shared__ __align__(8)  float ownh[2][2][SLICE];      // [unit][par][]
    __shared__ unsigned int cnt[2];
    __shared__ unsigned int ownflag[2];

    const int tid = threadIdx.x;

    if (blockIdx.x >= 32) {
        // ================= GEMM role (256 active threads) =================
        const int bid = blockIdx.x - 32;
        const int bmr = bid >> 5;                 // 0..63
        const int bn  = bid & 31;                 // 0..31
        const int bm  = (bmr & 1) ? (63 - (bmr >> 1)) : (bmr >> 1);  // both ends first
        const int fwd = (bn < 16);
        const float* __restrict__ W = fwd ? Wih_f : Wih_b;
        const int jbase = bn * 128 - (fwd ? 0 : 2048);
        const bool act = (tid < 256);

        if (tid < 128) srow[tid] = sentence[bm * 128 + tid];
        __syncthreads();

        const int lkk = tid & 15;
        const int lr  = (tid & 255) >> 4;
        int sr[8];
        float acc[8][8] = {};
        const float* wbase = W + (size_t)(jbase + lr * 8) * EMB + lkk;
        if (act) {
            #pragma unroll
            for (int i = 0; i < 8; ++i) sr[i] = srow[lr * 8 + i];
        }
        const int tx = tid & 15, ty = (tid & 255) >> 4;

        for (int kb = 0; kb < 32; ++kb) {
            const int k0 = kb * 16;
            if (act) {
                #pragma unroll
                for (int i = 0; i < 8; ++i) {
                    As[lkk][lr * 8 + i] = emb[(size_t)sr[i] * EMB + k0 + lkk];
                    Bs[lkk][lr * 8 + i] = wbase[(size_t)i * EMB + k0];
                }
            }
            __syncthreads();
            if (act) {
                #pragma unroll
                for (int kk = 0; kk < 16; ++kk) {
                    const float4 a0 = *(const float4*)&As[kk][ty * 8];
                    const float4 a1 = *(const float4*)&As[kk][ty * 8 + 4];
                    const float4 b0 = *(const float4*)&Bs[kk][tx * 8];
                    const float4 b1 = *(const float4*)&Bs[kk][tx * 8 + 4];
                    const float av[8] = {a0.x,a0.y,a0.z,a0.w,a1.x,a1.y,a1.z,a1.w};
                    const float bv[8] = {b0.x,b0.y,b0.z,b0.w,b1.x,b1.y,b1.z,b1.w};
                    #pragma unroll
                    for (int i = 0; i < 8; ++i)
                        #pragma unroll
                        for (int j = 0; j < 8; ++j)
                            acc[i][j] = fmaf(av[i], bv[j], acc[i][j]);
                }
            }
            __syncthreads();
        }

        if (act) {
            const float* b1p = fwd ? bih_f : bih_b;
            const float* b2p = fwd ? bhh_f : bhh_b;
            float bias[8];
            #pragma unroll
            for (int j = 0; j < 8; ++j) {
                const int jj = jbase + tx * 8 + j;
                bias[j] = b1p[jj] + b2p[jj];
            }
            #pragma unroll
            for (int i = 0; i < 8; ++i) {
                const int t = bm * 128 + ty * 8 + i;
                float4* dst = (float4*)&xprojb[(size_t)t * 4096 + bn * 128 + tx * 8];
                dst[0] = make_float4(acc[i][0] + bias[0], acc[i][1] + bias[1],
                                     acc[i][2] + bias[2], acc[i][3] + bias[3]);
                dst[1] = make_float4(acc[i][4] + bias[4], acc[i][5] + bias[5],
                                     acc[i][6] + bias[6], acc[i][7] + bias[7]);
            }
        }
        return;
    }

    // ================= LSTM role: 2 units (fwd, bwd) x 5 waves =================
    const int unit = (tid >= 320) ? 1 : 0;
    const int ut   = tid - unit * 320;
    const int lane = ut & 63;
    const int wvl  = ut >> 6;              // 0 = coordinator, 1..4 = k-chunk waves
    const int dir  = unit;
    const int sub  = blockIdx.x;           // 0..31
    const float* __restrict__ Whh = dir ? Whh_b : Whh_f;
    float* hs = hseq + (size_t)dir * T_SEQ * HDIM;

    if (tid == 0) { cnt[0] = 0u; cnt[1] = 0u; ownflag[0] = 0u; ownflag[1] = 0u; }
    __syncthreads();   // the ONLY full barrier in the LSTM role

    if (wvl == 0) {
        // ---- coordinator wave of this unit
        float c_state = 0.0f;
        const int  m   = lane & 15;
        const bool fin = lane < 16;
        const float* xrbase = xprojb + (size_t)dir * 2048 + sub * SLICE + m;
        #pragma unroll 1
        for (int s = 0; s < T_SEQ; ++s) {
            const int t = dir ? (T_SEQ - 1 - s) : s;
            const int p = s & 1;
            float xp0 = 0.f, xp1 = 0.f, xp2 = 0.f, xp3 = 0.f;
            const float* xr = xrbase + (size_t)t * 4096;
            if (fin) {   // issue early: latency hides under the spin
                xp0 = xr[0]; xp1 = xr[512]; xp2 = xr[1024]; xp3 = xr[1536];
            }
            const unsigned target = 4u * (unsigned)(s + 1);
            while (__hip_atomic_load(&cnt[unit], __ATOMIC_ACQUIRE,
                                     __HIP_MEMORY_SCOPE_WORKGROUP) < target) {}
            float h = 0.0f;
            if (fin) {
                // xproj produced concurrently by GEMM blocks: poison re-check
                while (__float_as_uint(xp0) == POISON32 ||
                       __float_as_uint(xp1) == POISON32 ||
                       __float_as_uint(xp2) == POISON32 ||
                       __float_as_uint(xp3) == POISON32) {
                    xp0 = __uint_as_float(ALOAD32((const unsigned*)(xr)));
                    xp1 = __uint_as_float(ALOAD32((const unsigned*)(xr + 512)));
                    xp2 = __uint_as_float(ALOAD32((const unsigned*)(xr + 1024)));
                    xp3 = __uint_as_float(ALOAD32((const unsigned*)(xr + 1536)));
                }
                const float si = partials[unit][p][0][m]      + partials[unit][p][1][m]
                               + partials[unit][p][2][m]      + partials[unit][p][3][m];
                const float sf = partials[unit][p][0][16 + m] + partials[unit][p][1][16 + m]
                               + partials[unit][p][2][16 + m] + partials[unit][p][3][16 + m];
                const float sg = partials[unit][p][0][32 + m] + partials[unit][p][1][32 + m]
                               + partials[unit][p][2][32 + m] + partials[unit][p][3][32 + m];
                const float so = partials[unit][p][0][48 + m] + partials[unit][p][1][48 + m]
                               + partials[unit][p][2][48 + m] + partials[unit][p][3][48 + m];
                const float i_ = fsig(si + xp0);
                const float f_ = fsig(sf + xp1);
                const float g_ = ftanh(sg + xp2);
                const float o_ = fsig(so + xp3);
                c_state = fmaf(f_, c_state, i_ * g_);
                h = o_ * ftanh(c_state);
                ownh[unit][p][m] = h;
            }
            if (lane == 0)   // release orders the ownh writes of this wave
                __hip_atomic_store(&ownflag[unit], (unsigned)(s + 1), __ATOMIC_RELEASE,
                                   __HIP_MEMORY_SCOPE_WORKGROUP);
            const float ha = __shfl(h, lane * 2);
            const float hb = __shfl(h, lane * 2 + 1);
            if (lane < 8) {
                unsigned long long* hp =
                    (unsigned long long*)(hs + (size_t)t * HDIM + sub * SLICE);
                ASTORE(hp + lane, pack2(ha, hb));
            }
        }
    } else {
        // ---- k-chunk wave of this unit
        const int c  = wvl - 1;
        const int rp = lane & 31;
        const int kh = lane >> 5;
        const int r0 = rp * 2;
        const int grow  = (r0 >> 4) * 512 + sub * SLICE + (r0 & 15);
        const int kbase = c * 128 + kh * 64;
        float w0[64], w1[64];
        {
            const float* src0 = Whh + (size_t)grow * 512 + kbase;
            const float* src1 = src0 + 512;
            #pragma unroll
            for (int j = 0; j < 16; ++j) {
                const float4 a = *(const float4*)(src0 + 4 * j);
                const float4 b = *(const float4*)(src1 + 4 * j);
                w0[4*j] = a.x; w0[4*j+1] = a.y; w0[4*j+2] = a.z; w0[4*j+3] = a.w;
                w1[4*j] = b.x; w1[4*j+1] = b.y; w1[4*j+2] = b.z; w1[4*j+3] = b.w;
            }
        }
        const bool ownlane = (c == (sub >> 3)) && ((lane >> 3) == (sub & 7));

        #pragma unroll 1
        for (int s = 0; s < T_SEQ; ++s) {
            const int t = dir ? (T_SEQ - 1 - s) : s;
            const int p = s & 1;
            float2 hv2;
            if (s == 0) {
                hv2 = make_float2(0.f, 0.f);
            } else if (ownlane) {
                while (__hip_atomic_load(&ownflag[unit], __ATOMIC_ACQUIRE,
                                         __HIP_MEMORY_SCOPE_WORKGROUP) < (unsigned)s) {}
                const int pp = (s - 1) & 1;
                const int j  = lane & 7;
                hv2.x = ownh[unit][pp][2 * j];
                hv2.y = ownh[unit][pp][2 * j + 1];
            } else {
                const int tprev = dir ? (t + 1) : (t - 1);
                const unsigned long long* hp =
                    (const unsigned long long*)(hs + (size_t)tprev * HDIM) + c * 64 + lane;
                unsigned long long u = ALOAD(hp);
                while (u == POISON64) u = ALOAD(hp);
                hv2 = unpack2(u);
            }
            ((float2*)&hst[unit][p][c][0])[lane] = hv2;

            float acc0 = 0.f, acc1 = 0.f;
            const float4* hb = (const float4*)&hst[unit][p][c][kh * 64];
            #pragma unroll
            for (int j = 0; j < 16; ++j) {
                const float4 hv = hb[j];
                acc0 = fmaf(w0[4*j],   hv.x, acc0); acc1 = fmaf(w1[4*j],   hv.x, acc1);
                acc0 = fmaf(w0[4*j+1], hv.y, acc0); acc1 = fmaf(w1[4*j+1], hv.y, acc1);
                acc0 = fmaf(w0[4*j+2], hv.z, acc0); acc1 = fmaf(w1[4*j+2], hv.z, acc1);
                acc0 = fmaf(w0[4*j+3], hv.w, acc0); acc1 = fmaf(w1[4*j+3], hv.w, acc1);
            }
            acc0 += __shfl_xor(acc0, 32);
            acc1 += __shfl_xor(acc1, 32);
            if (lane < 32)
                ((float2*)&partials[unit][p][c][0])[lane] = make_float2(acc0, acc1);
            if (lane == 0)
                __hip_atomic_fetch_add(&cnt[unit], 1u, __ATOMIC_RELEASE,
                                       __HIP_MEMORY_SCOPE_WORKGROUP);
        }
    }
}

// ---------------------------------------------------------------- K3: feats
__global__ __launch_bounds__(256) void feats_kernel(
    const float* __restrict__ hseq, const float* __restrict__ W_out,
    const float* __restrict__ b_out, float* __restrict__ feats)
{
    const int idx = blockIdx.x * 256 + threadIdx.x;   // (t, n)
    if (idx >= T_SEQ * 9) return;
    const int t = idx / 9;
    const int n = idx - t * 9;
    const float4* hf = (const float4*)(hseq + (size_t)t * HDIM);
    const float4* hb = (const float4*)(hseq + (size_t)(T_SEQ + t) * HDIM);
    const float4* wf = (const float4*)(W_out + (size_t)n * 1024);
    const float4* wb = wf + 128;
    float acc = b_out[n];
    #pragma unroll 8
    for (int i = 0; i < 128; ++i) {
        const float4 a = hf[i], w = wf[i];
        acc = fmaf(a.x, w.x, acc); acc = fmaf(a.y, w.y, acc);
        acc = fmaf(a.z, w.z, acc); acc = fmaf(a.w, w.w, acc);
    }
    #pragma unroll 8
    for (int i = 0; i < 128; ++i) {
        const float4 a = hb[i], w = wb[i];
        acc = fmaf(a.x, w.x, acc); acc = fmaf(a.y, w.y, acc);
        acc = fmaf(a.z, w.z, acc); acc = fmaf(a.w, w.w, acc);
    }
    feats[idx] = acc;
}

// --------------------------------------------------------------- K4: viterbi
__global__ __launch_bounds__(64) void viterbi_kernel(
    const float* __restrict__ feats, const float* __restrict__ trans,
    unsigned long long* __restrict__ bpw, float* __restrict__ out)
{
    const int lane = threadIdx.x;
    __shared__ __align__(16) float flds[1024 * 9];
    __shared__ unsigned char path_lds[T_SEQ];

    float tr[9];
    #pragma unroll
    for (int p = 0; p < 9; ++p) tr[p] = 0.f;
    float tstop = 0.f;
    if (lane < 9) {
        #pragma unroll
        for (int p = 0; p < 9; ++p) tr[p] = trans[lane * 9 + p];
        tstop = trans[8 * 9 + lane];
    }
    float fv = (lane == 7) ? 0.0f : -10000.0f;        // START_IDX = 7

    for (int ch = 0; ch < 8; ++ch) {
        const float4* src = (const float4*)(feats + (size_t)ch * 9216);
        #pragma unroll
        for (int i = 0; i < 36; ++i)
            ((float4*)flds)[lane + i * 64] = src[lane + i * 64];
        __syncthreads();

        for (int tt = 0; tt < 1024; ++tt) {
            const int t = ch * 1024 + tt;
            const float f0 = __shfl(fv, 0), f1 = __shfl(fv, 1), f2 = __shfl(fv, 2);
            const float f3 = __shfl(fv, 3), f4 = __shfl(fv, 4), f5 = __shfl(fv, 5);
            const float f6 = __shfl(fv, 6), f7 = __shfl(fv, 7), f8 = __shfl(fv, 8);
            const float s0 = f0 + tr[0], s1 = f1 + tr[1], s2 = f2 + tr[2];
            const float s3 = f3 + tr[3], s4 = f4 + tr[4], s5 = f5 + tr[5];
            const float s6 = f6 + tr[6], s7 = f7 + tr[7], s8 = f8 + tr[8];
            const float mx = fmaxf(fmaxf(fmaxf(fmaxf(s0, s1), fmaxf(s2, s3)),
                                         fmaxf(fmaxf(s4, s5), fmaxf(s6, s7))), s8);
            const unsigned bits =
                (s0 >= mx ? 1u : 0u)   | (s1 >= mx ? 2u : 0u)   | (s2 >= mx ? 4u : 0u) |
                (s3 >= mx ? 8u : 0u)   | (s4 >= mx ? 16u : 0u)  | (s5 >= mx ? 32u : 0u) |
                (s6 >= mx ? 64u : 0u)  | (s7 >= mx ? 128u : 0u) | (s8 >= mx ? 256u : 0u);
            const int bi = __ffs(bits) - 1;
            const float feat = (lane < 9) ? flds[tt * 9 + lane] : 0.0f;
            fv = mx + feat;
            const unsigned long long b0 = __ballot(bi & 1);
            const unsigned long long b1 = __ballot(bi & 2);
            const unsigned long long b2 = __ballot(bi & 4);
            const unsigned long long b3 = __ballot(bi & 8);
            if (lane == 0) {
                bpw[t] = (b0 & 511ull) | ((b1 & 511ull) << 9) |
                         ((b2 & 511ull) << 18) | ((b3 & 511ull) << 27);
            }
        }
        __syncthreads();
    }

    const float term = fv + tstop;
    const float t0 = __shfl(term, 0), t1 = __shfl(term, 1), t2 = __shfl(term, 2);
    const float t3 = __shfl(term, 3), t4 = __shfl(term, 4), t5 = __shfl(term, 5);
    const float t6 = __shfl(term, 6), t7 = __shfl(term, 7), t8 = __shfl(term, 8);
    const float mxt = fmaxf(fmaxf(fmaxf(fmaxf(t0, t1), fmaxf(t2, t3)),
                                  fmaxf(fmaxf(t4, t5), fmaxf(t6, t7))), t8);
    const unsigned bitst =
        (t0 >= mxt ? 1u : 0u)   | (t1 >= mxt ? 2u : 0u)   | (t2 >= mxt ? 4u : 0u) |
        (t3 >= mxt ? 8u : 0u)   | (t4 >= mxt ? 16u : 0u)  | (t5 >= mxt ? 32u : 0u) |
        (t6 >= mxt ? 64u : 0u)  | (t7 >= mxt ? 128u : 0u) | (t8 >= mxt ? 256u : 0u);
    const int best = __ffs(bitst) - 1;

    if (lane == 0) {
        out[0] = mxt;
        int c = best;
        path_lds[T_SEQ - 1] = (unsigned char)c;
        for (int thi = T_SEQ - 2; thi >= 15; thi -= 16) {
            const int tlo = thi - 15;
            unsigned long long wbuf[16];
            #pragma unroll
            for (int i = 0; i < 16; ++i) wbuf[i] = bpw[tlo + 1 + i];
            #pragma unroll
            for (int i = 15; i >= 0; --i) {
                const unsigned long long wvv = wbuf[i];
                c = (int)((wvv >> c) & 1ull) |
                    ((int)((wvv >> (9 + c)) & 1ull) << 1) |
                    ((int)((wvv >> (18 + c)) & 1ull) << 2) |
                    ((int)((wvv >> (27 + c)) & 1ull) << 3);
                path_lds[tlo + i] = (unsigned char)c;
            }
        }
        for (int t2i = 14; t2i >= 0; --t2i) {
            const unsigned long long wvv = bpw[t2i + 1];
            c = (int)((wvv >> c) & 1ull) |
                ((int)((wvv >> (9 + c)) & 1ull) << 1) |
                ((int)((wvv >> (18 + c)) & 1ull) << 2) |
                ((int)((wvv >> (27 + c)) & 1ull) << 3);
            path_lds[t2i] = (unsigned char)c;
        }
    }
    __syncthreads();
    #pragma unroll 4
    for (int i = 0; i < T_SEQ / 64; ++i) {
        const int t = i * 64 + lane;
        out[1 + t] = (float)path_lds[t];
    }
}

// ------------------------------------------------------------------- launch
extern "C" void kernel_launch(void* const* d_in, const int* in_sizes, int n_in,
                              void* d_out, int out_size, void* d_ws, size_t ws_size,
                              hipStream_t stream)
{
    (void)in_sizes; (void)n_in; (void)out_size; (void)ws_size;

    const int*   sentence = (const int*)  d_in[0];
    const float* emb      = (const float*)d_in[1];
    const float* Wih_f    = (const float*)d_in[2];
    const float* Whh_f    = (const float*)d_in[3];
    const float* bih_f    = (const float*)d_in[4];
    const float* bhh_f    = (const float*)d_in[5];
    const float* Wih_b    = (const float*)d_in[6];
    const float* Whh_b    = (const float*)d_in[7];
    const float* bih_b    = (const float*)d_in[8];
    const float* bhh_b    = (const float*)d_in[9];
    const float* W_out    = (const float*)d_in[10];
    const float* b_out    = (const float*)d_in[11];
    const float* trans    = (const float*)d_in[12];

    float* ws      = (float*)d_ws;
    float* xprojb  = ws;                                        // 8192*4096
    float* hseq    = ws + (size_t)T_SEQ * 4096;                 // 2*8192*512
    float* feats   = hseq + (size_t)2 * T_SEQ * HDIM;           // 8192*9
    unsigned long long* bpw = (unsigned long long*)(feats + (size_t)T_SEQ * 9);

    // poison BOTH producer-consumer buffers every launch (graph replay safety)
    hipMemsetAsync(xprojb, 0x7F, (size_t)T_SEQ * 4096 * sizeof(float), stream);
    hipMemsetAsync(hseq,   0x7F, (size_t)2 * T_SEQ * HDIM * sizeof(float), stream);

    fused_main<<<dim3(32 + 2048), 640, 0, stream>>>(
        sentence, emb, Wih_f, Wih_b, bih_f, bhh_f, bih_b, bhh_b,
        Whh_f, Whh_b, xprojb, hseq);

    feats_kernel<<<dim3((T_SEQ * 9 + 255) / 256), 256, 0, stream>>>(
        hseq, W_out, b_out, feats);

    viterbi_kernel<<<dim3(1), 64, 0, stream>>>(feats, trans, bpw, (float*)d_out);
}

// Round 12
// 17022.566 us; speedup vs baseline: 1.5972x; 1.1751x over previous
//
#include <hip/hip_runtime.h>
#include <hip/hip_bf16.h>

// BiLSTM(512/dir, T=8192) + linear(9) + Viterbi decode.
//  K1 gemm_xproj : 128x128 tile, BK=32, 8x8 register blocking, float4 staging,
//                  2 blocks/CU (VALU fp32; no fp32 MFMA on CDNA4)
//  K2 lstm_scan  : R2/R3-proven structure (best measured: 14.4ms): 64 persistent
//                  blocks (32/dir) x 320 threads; wave0 coordinator, waves 1..4
//                  k-chunks with Whh in VGPRs; poison-poll h via agent relaxed u64;
//                  LDS staging + monotonic cnt (rel/acq); own-slice LDS forward.
//  K3 feats      : feats[t,n] = [h_f|h_b] @ W_out^T + b_out
//  K4 viterbi    : single wave; backpointers packed 4b x 9 into u64/step.
//
// ws layout (floats):
//   [0)                 xprojb   8192*4096            = 128 MB
//   [+8192*4096)        h_seq    2*8192*512           =  32 MB (poisoned 0x7F each launch)
//   [+2*8192*512)       feats    8192*9
//   [then]              bpw      8192 u64

#define T_SEQ   8192
#define EMB     512
#define HDIM    512
#define SLICE   16
#define POISON64 0x7F7F7F7F7F7F7F7Full  // |h|<1 so never produced

// ---------------------------------------------------------------- K1: GEMM
__global__ __launch_bounds__(256, 2) void gemm_xproj(
    const int* __restrict__ sentence, const float* __restrict__ emb,
    const float* __restrict__ Wih_f, const float* __restrict__ Wih_b,
    const float* __restrict__ bih_f, const float* __restrict__ bhh_f,
    const float* __restrict__ bih_b, const float* __restrict__ bhh_b,
    float* __restrict__ xprojb)
{
    __shared__ float As[32][132];      // [k][row], pad 132
    __shared__ float Bs[32][132];
    __shared__ int   srow[128];

    const int tid = threadIdx.x;
    const int bm = blockIdx.x;          // 64 tiles of 128 t
    const int bn = blockIdx.y;          // 32 tiles of 128 j (0..15 fwd, 16..31 bwd)
    const int fwd = (bn < 16);
    const float* __restrict__ W = fwd ? Wih_f : Wih_b;
    const int jbase = bn * 128 - (fwd ? 0 : 2048);

    if (tid < 128) srow[tid] = sentence[bm * 128 + tid];
    __syncthreads();

    // staging map: thread covers rows sr_r + i*32 (i=0..3), k-float4 at sk4
    const int sr_r = tid >> 3;          // 0..31
    const int sk4  = (tid & 7) * 4;     // 0,4,..,28
    const float* arow[4];
    const float* brow[4];
    #pragma unroll
    for (int i = 0; i < 4; ++i) {
        arow[i] = emb + (size_t)srow[sr_r + i * 32] * EMB + sk4;
        brow[i] = W + (size_t)(jbase + sr_r + i * 32) * EMB + sk4;
    }

    const int tx = tid & 15, ty = tid >> 4;
    float acc[8][8] = {};

    for (int kb = 0; kb < 16; ++kb) {
        const int k0 = kb * 32;
        #pragma unroll
        for (int i = 0; i < 4; ++i) {
            const int r = sr_r + i * 32;
            const float4 av = *(const float4*)(arow[i] + k0);
            const float4 bv = *(const float4*)(brow[i] + k0);
            As[sk4 + 0][r] = av.x; As[sk4 + 1][r] = av.y;
            As[sk4 + 2][r] = av.z; As[sk4 + 3][r] = av.w;
            Bs[sk4 + 0][r] = bv.x; Bs[sk4 + 1][r] = bv.y;
            Bs[sk4 + 2][r] = bv.z; Bs[sk4 + 3][r] = bv.w;
        }
        __syncthreads();
        #pragma unroll 4
        for (int kk = 0; kk < 32; ++kk) {
            const float4 a0 = *(const float4*)&As[kk][ty * 8];
            const float4 a1 = *(const float4*)&As[kk][ty * 8 + 4];
            const float4 b0 = *(const float4*)&Bs[kk][tx * 8];
            const float4 b1 = *(const float4*)&Bs[kk][tx * 8 + 4];
            const float av[8] = {a0.x,a0.y,a0.z,a0.w,a1.x,a1.y,a1.z,a1.w};
            const float bv[8] = {b0.x,b0.y,b0.z,b0.w,b1.x,b1.y,b1.z,b1.w};
            #pragma unroll
            for (int i = 0; i < 8; ++i)
                #pragma unroll
                for (int j = 0; j < 8; ++j)
                    acc[i][j] = fmaf(av[i], bv[j], acc[i][j]);
        }
        __syncthreads();
    }

    const float* b1p = fwd ? bih_f : bih_b;
    const float* b2p = fwd ? bhh_f : bhh_b;
    float bias[8];
    #pragma unroll
    for (int j = 0; j < 8; ++j) {
        const int jj = jbase + tx * 8 + j;
        bias[j] = b1p[jj] + b2p[jj];
    }
    #pragma unroll
    for (int i = 0; i < 8; ++i) {
        const int t = bm * 128 + ty * 8 + i;
        float4* dst = (float4*)&xprojb[(size_t)t * 4096 + bn * 128 + tx * 8];
        dst[0] = make_float4(acc[i][0] + bias[0], acc[i][1] + bias[1],
                             acc[i][2] + bias[2], acc[i][3] + bias[3]);
        dst[1] = make_float4(acc[i][4] + bias[4], acc[i][5] + bias[5],
                             acc[i][6] + bias[6], acc[i][7] + bias[7]);
    }
}

// ------------------------------------------------------------- K2: LSTM scan
__device__ __forceinline__ float fsig(float x) { return 1.0f / (1.0f + __expf(-x)); }
__device__ __forceinline__ float ftanh(float x) {
    const float e = __expf(-2.0f * fabsf(x));
    return copysignf((1.0f - e) / (1.0f + e), x);
}
__device__ __forceinline__ unsigned long long pack2(float a, float b) {
    return (unsigned long long)__float_as_uint(a) |
           ((unsigned long long)__float_as_uint(b) << 32);
}

__global__ __launch_bounds__(320, 1) void lstm_scan(
    const float* __restrict__ xprojb,
    const float* __restrict__ Whh_f, const float* __restrict__ Whh_b,
    float* __restrict__ hseq)
{
    const int tid  = threadIdx.x;
    const int lane = tid & 63;
    const int wv   = tid >> 6;          // 0 = coordinator, 1..4 = k-chunk waves
    const int blk  = blockIdx.x;        // 0..63
    const int dir  = blk & 1;
    const int sub  = blk >> 1;          // 0..31
    const float* __restrict__ Whh = dir ? Whh_b : Whh_f;
    float* hs = hseq + (size_t)dir * T_SEQ * HDIM;

    __shared__ __align__(16) float hst[2][4][128];      // staged h chunks (per wave)
    __shared__ __align__(16) float partials[2][4][64];  // per-chunk row partial sums
    __shared__ __align__(8)  float ownh[2][SLICE];      // own slice LDS forward
    __shared__ unsigned int cnt;                        // monotonic: 4 per step
    __shared__ unsigned int ownflag;                    // monotonic: 1 per step

    if (tid == 0) { cnt = 0u; ownflag = 0u; }
    __syncthreads();   // the ONLY barrier in this kernel

    if (wv == 0) {
        // ---- coordinator wave: finalize gates, own c-state, publish h slice
        float c_state = 0.0f;
        const int  m   = lane & 15;
        const bool fin = lane < 16;
        #pragma unroll 1
        for (int s = 0; s < T_SEQ; ++s) {
            const int t = dir ? (T_SEQ - 1 - s) : s;
            const int p = s & 1;
            float xp0 = 0.f, xp1 = 0.f, xp2 = 0.f, xp3 = 0.f;
            if (fin) {   // issue early: latency hides under the spin
                const float* xr = xprojb + (size_t)t * 4096 + dir * 2048 + sub * SLICE + m;
                xp0 = xr[0]; xp1 = xr[512]; xp2 = xr[1024]; xp3 = xr[1536];
            }
            const unsigned target = 4u * (unsigned)(s + 1);
            while (__hip_atomic_load(&cnt, __ATOMIC_ACQUIRE,
                                     __HIP_MEMORY_SCOPE_WORKGROUP) < target) {}
            float h = 0.0f;
            if (fin) {
                const float si = partials[p][0][m]      + partials[p][1][m]
                               + partials[p][2][m]      + partials[p][3][m];
                const float sf = partials[p][0][16 + m] + partials[p][1][16 + m]
                               + partials[p][2][16 + m] + partials[p][3][16 + m];
                const float sg = partials[p][0][32 + m] + partials[p][1][32 + m]
                               + partials[p][2][32 + m] + partials[p][3][32 + m];
                const float so = partials[p][0][48 + m] + partials[p][1][48 + m]
                               + partials[p][2][48 + m] + partials[p][3][48 + m];
                const float i_ = fsig(si + xp0);
                const float f_ = fsig(sf + xp1);
                const float g_ = ftanh(sg + xp2);
                const float o_ = fsig(so + xp3);
                c_state = fmaf(f_, c_state, i_ * g_);
                h = o_ * ftanh(c_state);
                ownh[p][m] = h;
            }
            if (lane == 0)   // release orders the ownh writes of this wave
                __hip_atomic_store(&ownflag, (unsigned)(s + 1), __ATOMIC_RELEASE,
                                   __HIP_MEMORY_SCOPE_WORKGROUP);
            // pack h pairs and publish to global (u64 atomic -> no tearing)
            const float ha = __shfl(h, lane * 2);
            const float hb = __shfl(h, lane * 2 + 1);
            if (lane < 8) {
                unsigned long long* hp =
                    (unsigned long long*)(hs + (size_t)t * HDIM + sub * SLICE);
                __hip_atomic_store(hp + lane, pack2(ha, hb), __ATOMIC_RELAXED,
                                   __HIP_MEMORY_SCOPE_AGENT);
            }
        }
    } else {
        // ---- k-chunk wave: poll its 128 h values, partial matvec, ds partials
        const int c  = wv - 1;          // chunk 0..3, k in [128c, 128c+128)
        const int rp = lane & 31;       // row pair
        const int kh = lane >> 5;       // k half (64)
        const int r0 = rp * 2;          // block-local rows r0, r0+1 (same gate)
        const int grow  = (r0 >> 4) * 512 + sub * SLICE + (r0 & 15);
        const int kbase = c * 128 + kh * 64;
        float w0[64], w1[64];
        {
            const float* src0 = Whh + (size_t)grow * 512 + kbase;
            const float* src1 = src0 + 512;
            #pragma unroll
            for (int j = 0; j < 16; ++j) {
                const float4 a = *(const float4*)(src0 + 4 * j);
                const float4 b = *(const float4*)(src1 + 4 * j);
                w0[4*j] = a.x; w0[4*j+1] = a.y; w0[4*j+2] = a.z; w0[4*j+3] = a.w;
                w1[4*j] = b.x; w1[4*j+1] = b.y; w1[4*j+2] = b.z; w1[4*j+3] = b.w;
            }
        }
        #pragma unroll
        for (int j = 0; j < 64; ++j) {
            asm volatile("" : "+v"(w0[j]));
            asm volatile("" : "+v"(w1[j]));
        }

        // lanes whose u64 pair is produced by THIS block -> LDS fast path
        const bool ownlane = (c == (sub >> 3)) && ((lane >> 3) == (sub & 7));

        #pragma unroll 1
        for (int s = 0; s < T_SEQ; ++s) {
            const int t = dir ? (T_SEQ - 1 - s) : s;
            const int p = s & 1;
            float2 hv2;
            if (s == 0) {
                hv2 = make_float2(0.f, 0.f);
            } else if (ownlane) {
                while (__hip_atomic_load(&ownflag, __ATOMIC_ACQUIRE,
                                         __HIP_MEMORY_SCOPE_WORKGROUP) < (unsigned)s) {}
                const int pp = (s - 1) & 1;
                const int j  = lane & 7;
                hv2.x = ownh[pp][2 * j];
                hv2.y = ownh[pp][2 * j + 1];
            } else {
                const int tprev = dir ? (t + 1) : (t - 1);
                const unsigned long long* hp =
                    (const unsigned long long*)(hs + (size_t)tprev * HDIM) + c * 64 + lane;
                unsigned long long u = __hip_atomic_load(hp, __ATOMIC_RELAXED,
                                                         __HIP_MEMORY_SCOPE_AGENT);
                while (u == POISON64)
                    u = __hip_atomic_load(hp, __ATOMIC_RELAXED, __HIP_MEMORY_SCOPE_AGENT);
                hv2.x = __uint_as_float((unsigned)(u & 0xffffffffull));
                hv2.y = __uint_as_float((unsigned)(u >> 32));
            }
            ((float2*)&hst[p][c][0])[lane] = hv2;   // wave-local; lgkmcnt orders RAW

            float acc0 = 0.f, acc1 = 0.f;
            const float4* hb = (const float4*)&hst[p][c][kh * 64];
            #pragma unroll
            for (int j = 0; j < 16; ++j) {
                const float4 hv = hb[j];
                acc0 = fmaf(w0[4*j],   hv.x, acc0); acc1 = fmaf(w1[4*j],   hv.x, acc1);
                acc0 = fmaf(w0[4*j+1], hv.y, acc0); acc1 = fmaf(w1[4*j+1], hv.y, acc1);
                acc0 = fmaf(w0[4*j+2], hv.z, acc0); acc1 = fmaf(w1[4*j+2], hv.z, acc1);
                acc0 = fmaf(w0[4*j+3], hv.w, acc0); acc1 = fmaf(w1[4*j+3], hv.w, acc1);
            }
            acc0 += __shfl_xor(acc0, 32);
            acc1 += __shfl_xor(acc1, 32);
            if (lane < 32)
                ((float2*)&partials[p][c][0])[lane] = make_float2(acc0, acc1);
            if (lane == 0)   // release: waits this wave's ds writes first
                __hip_atomic_fetch_add(&cnt, 1u, __ATOMIC_RELEASE,
                                       __HIP_MEMORY_SCOPE_WORKGROUP);
        }
    }
}

// ---------------------------------------------------------------- K3: feats
__global__ __launch_bounds__(256) void feats_kernel(
    const float* __restrict__ hseq, const float* __restrict__ W_out,
    const float* __restrict__ b_out, float* __restrict__ feats)
{
    const int idx = blockIdx.x * 256 + threadIdx.x;   // (t, n)
    if (idx >= T_SEQ * 9) return;
    const int t = idx / 9;
    const int n = idx - t * 9;
    const float4* hf = (const float4*)(hseq + (size_t)t * HDIM);
    const float4* hb = (const float4*)(hseq + (size_t)(T_SEQ + t) * HDIM);
    const float4* wf = (const float4*)(W_out + (size_t)n * 1024);
    const float4* wb = wf + 128;
    float acc = b_out[n];
    #pragma unroll 8
    for (int i = 0; i < 128; ++i) {
        const float4 a = hf[i], w = wf[i];
        acc = fmaf(a.x, w.x, acc); acc = fmaf(a.y, w.y, acc);
        acc = fmaf(a.z, w.z, acc); acc = fmaf(a.w, w.w, acc);
    }
    #pragma unroll 8
    for (int i = 0; i < 128; ++i) {
        const float4 a = hb[i], w = wb[i];
        acc = fmaf(a.x, w.x, acc); acc = fmaf(a.y, w.y, acc);
        acc = fmaf(a.z, w.z, acc); acc = fmaf(a.w, w.w, acc);
    }
    feats[idx] = acc;
}

// --------------------------------------------------------------- K4: viterbi
__global__ __launch_bounds__(64) void viterbi_kernel(
    const float* __restrict__ feats, const float* __restrict__ trans,
    unsigned long long* __restrict__ bpw, float* __restrict__ out)
{
    const int lane = threadIdx.x;
    __shared__ __align__(16) float flds[1024 * 9];
    __shared__ unsigned char path_lds[T_SEQ];

    float tr[9];
    #pragma unroll
    for (int p = 0; p < 9; ++p) tr[p] = 0.f;
    float tstop = 0.f;
    if (lane < 9) {
        #pragma unroll
        for (int p = 0; p < 9; ++p) tr[p] = trans[lane * 9 + p];
        tstop = trans[8 * 9 + lane];
    }
    float fv = (lane == 7) ? 0.0f : -10000.0f;        // START_IDX = 7

    for (int ch = 0; ch < 8; ++ch) {
        const float4* src = (const float4*)(feats + (size_t)ch * 9216);
        #pragma unroll
        for (int i = 0; i < 36; ++i)
            ((float4*)flds)[lane + i * 64] = src[lane + i * 64];
        __syncthreads();

        for (int tt = 0; tt < 1024; ++tt) {
            const int t = ch * 1024 + tt;
            const float f0 = __shfl(fv, 0), f1 = __shfl(fv, 1), f2 = __shfl(fv, 2);
            const float f3 = __shfl(fv, 3), f4 = __shfl(fv, 4), f5 = __shfl(fv, 5);
            const float f6 = __shfl(fv, 6), f7 = __shfl(fv, 7), f8 = __shfl(fv, 8);
            const float s0 = f0 + tr[0], s1 = f1 + tr[1], s2 = f2 + tr[2];
            const float s3 = f3 + tr[3], s4 = f4 + tr[4], s5 = f5 + tr[5];
            const float s6 = f6 + tr[6], s7 = f7 + tr[7], s8 = f8 + tr[8];
            const float mx = fmaxf(fmaxf(fmaxf(fmaxf(s0, s1), fmaxf(s2, s3)),
                                         fmaxf(fmaxf(s4, s5), fmaxf(s6, s7))), s8);
            const unsigned bits =
                (s0 >= mx ? 1u : 0u)   | (s1 >= mx ? 2u : 0u)   | (s2 >= mx ? 4u : 0u) |
                (s3 >= mx ? 8u : 0u)   | (s4 >= mx ? 16u : 0u)  | (s5 >= mx ? 32u : 0u) |
                (s6 >= mx ? 64u : 0u)  | (s7 >= mx ? 128u : 0u) | (s8 >= mx ? 256u : 0u);
            const int bi = __ffs(bits) - 1;
            const float feat = (lane < 9) ? flds[tt * 9 + lane] : 0.0f;
            fv = mx + feat;
            const unsigned long long b0 = __ballot(bi & 1);
            const unsigned long long b1 = __ballot(bi & 2);
            const unsigned long long b2 = __ballot(bi & 4);
            const unsigned long long b3 = __ballot(bi & 8);
            if (lane == 0) {
                bpw[t] = (b0 & 511ull) | ((b1 & 511ull) << 9) |
                         ((b2 & 511ull) << 18) | ((b3 & 511ull) << 27);
            }
        }
        __syncthreads();
    }

    const float term = fv + tstop;
    const float t0 = __shfl(term, 0), t1 = __shfl(term, 1), t2 = __shfl(term, 2);
    const float t3 = __shfl(term, 3), t4 = __shfl(term, 4), t5 = __shfl(term, 5);
    const float t6 = __shfl(term, 6), t7 = __shfl(term, 7), t8 = __shfl(term, 8);
    const float mxt = fmaxf(fmaxf(fmaxf(fmaxf(t0, t1), fmaxf(t2, t3)),
                                  fmaxf(fmaxf(t4, t5), fmaxf(t6, t7))), t8);
    const unsigned bitst =
        (t0 >= mxt ? 1u : 0u)   | (t1 >= mxt ? 2u : 0u)   | (t2 >= mxt ? 4u : 0u) |
        (t3 >= mxt ? 8u : 0u)   | (t4 >= mxt ? 16u : 0u)  | (t5 >= mxt ? 32u : 0u) |
        (t6 >= mxt ? 64u : 0u)  | (t7 >= mxt ? 128u : 0u) | (t8 >= mxt ? 256u : 0u);
    const int best = __ffs(bitst) - 1;

    if (lane == 0) {
        out[0] = mxt;
        int c = best;
        path_lds[T_SEQ - 1] = (unsigned char)c;
        for (int thi = T_SEQ - 2; thi >= 15; thi -= 16) {
            const int tlo = thi - 15;
            unsigned long long wbuf[16];
            #pragma unroll
            for (int i = 0; i < 16; ++i) wbuf[i] = bpw[tlo + 1 + i];
            #pragma unroll
            for (int i = 15; i >= 0; --i) {
                const unsigned long long wvv = wbuf[i];
                c = (int)((wvv >> c) & 1ull) |
                    ((int)((wvv >> (9 + c)) & 1ull) << 1) |
                    ((int)((wvv >> (18 + c)) & 1ull) << 2) |
                    ((int)((wvv >> (27 + c)) & 1ull) << 3);
                path_lds[tlo + i] = (unsigned char)c;
            }
        }
        for (int t2i = 14; t2i >= 0; --t2i) {
            const unsigned long long wvv = bpw[t2i + 1];
            c = (int)((wvv >> c) & 1ull) |
                ((int)((wvv >> (9 + c)) & 1ull) << 1) |
                ((int)((wvv >> (18 + c)) & 1ull) << 2) |
                ((int)((wvv >> (27 + c)) & 1ull) << 3);
            path_lds[t2i] = (unsigned char)c;
        }
    }
    __syncthreads();
    #pragma unroll 4
    for (int i = 0; i < T_SEQ / 64; ++i) {
        const int t = i * 64 + lane;
        out[1 + t] = (float)path_lds[t];
    }
}

// ------------------------------------------------------------------- launch
extern "C" void kernel_launch(void* const* d_in, const int* in_sizes, int n_in,
                              void* d_out, int out_size, void* d_ws, size_t ws_size,
                              hipStream_t stream)
{
    (void)in_sizes; (void)n_in; (void)out_size; (void)ws_size;

    const int*   sentence = (const int*)  d_in[0];
    const float* emb      = (const float*)d_in[1];
    const float* Wih_f    = (const float*)d_in[2];
    const float* Whh_f    = (const float*)d_in[3];
    const float* bih_f    = (const float*)d_in[4];
    const float* bhh_f    = (const float*)d_in[5];
    const float* Wih_b    = (const float*)d_in[6];
    const float* Whh_b    = (const float*)d_in[7];
    const float* bih_b    = (const float*)d_in[8];
    const float* bhh_b    = (const float*)d_in[9];
    const float* W_out    = (const float*)d_in[10];
    const float* b_out    = (const float*)d_in[11];
    const float* trans    = (const float*)d_in[12];

    float* ws      = (float*)d_ws;
    float* xprojb  = ws;                                        // 8192*4096
    float* hseq    = ws + (size_t)T_SEQ * 4096;                 // 2*8192*512
    float* feats   = hseq + (size_t)2 * T_SEQ * HDIM;           // 8192*9
    unsigned long long* bpw = (unsigned long long*)(feats + (size_t)T_SEQ * 9);

    // re-poison the h exchange buffer every launch (graph replay safety)
    hipMemsetAsync(hseq, 0x7F, (size_t)2 * T_SEQ * HDIM * sizeof(float), stream);

    gemm_xproj<<<dim3(64, 32), 256, 0, stream>>>(
        sentence, emb, Wih_f, Wih_b, bih_f, bhh_f, bih_b, bhh_b, xprojb);

    lstm_scan<<<dim3(64), 320, 0, stream>>>(
        xprojb, Whh_f, Whh_b, hseq);

    feats_kernel<<<dim3((T_SEQ * 9 + 255) / 256), 256, 0, stream>>>(
        hseq, W_out, b_out, feats);

    viterbi_kernel<<<dim3(1), 64, 0, stream>>>(feats, trans, bpw, (float*)d_out);
}